// Round 9
// baseline (96.090 us; speedup 1.0000x reference)
//
#include <hip/hip_runtime.h>
#include <hip/hip_bf16.h>
#include <math.h>

typedef __bf16 bf16x8 __attribute__((ext_vector_type(8)));
typedef float f32x4 __attribute__((ext_vector_type(4)));

namespace {
constexpr int BN   = 8192;   // batch columns
constexpr int DK   = 128;    // feature dim
constexpr int NCAT = 8192;   // cat rows
constexpr int SRC  = 4;      // source chunks
constexpr int RG   = 16;     // row groups (512 rows each)
constexpr int NIT  = 16;     // 16-row strips per 256-row wave half
constexpr float LOG2E = 1.4426950408889634f;
}

__device__ __forceinline__ float4 ld4(const float* p) {
    return *reinterpret_cast<const float4*>(p);
}

// fp32 -> bf16 (RNE), row-major, both inputs in one launch
__global__ __launch_bounds__(256) void k_convert2(const float* __restrict__ x,
                                                  const float* __restrict__ cat,
                                                  unsigned short* __restrict__ xb,
                                                  unsigned short* __restrict__ catb) {
    const int i = blockIdx.x * 256 + threadIdx.x;
    const int nx = BN * DK / 8;
    const float* src;
    unsigned short* dst;
    int j;
    if (i < nx) { src = x; dst = xb; j = i; }
    else        { src = cat; dst = catb; j = i - nx; }
    const float4 a = ld4(src + (size_t)j * 8);
    const float4 b = ld4(src + (size_t)j * 8 + 4);
    float vals[8] = {a.x, a.y, a.z, a.w, b.x, b.y, b.z, b.w};
    union { unsigned short u[8]; uint4 v; } o;
#pragma unroll
    for (int q = 0; q < 8; ++q) {
        __hip_bfloat16 h = __float2bfloat16(vals[q]);
        o.u[q] = *reinterpret_cast<unsigned short*>(&h);
    }
    *reinterpret_cast<uint4*>(&dst[(size_t)j * 8]) = o.v;
}

// MFMA pass, no LDS staging. Block = 128 cols x 512 rows, 4 waves.
// Wave w: col-half ch=w&1 (64 cols, Bf[4][4]=64 VGPR pinned in registers via
// empty-asm), row-half rh=w>>1 (256 rows in 16-row strips, reg-double-buffered
// prefetch). No barriers in the main loop; waves fully independent.
// No softmax max needed: |d|/norm4 <= 1 provably (norm4 >= max|d|).
// PASS==1: outA = partial sum(d^4)
// PASS==2: outA = partial Z, outB = partial sum(y*exp); norms from pp4in in-block
template <int PASS>
__global__ __launch_bounds__(256, 3) void k_pass(
    const unsigned short* __restrict__ xb,    // [BN][DK] bf16 row-major
    const unsigned short* __restrict__ catb,  // [NCAT][DK] bf16 row-major
    const float* __restrict__ y,
    const float* __restrict__ pp4in,          // pass2: [RG][BN]
    float* __restrict__ outA,
    float* __restrict__ outB) {
    __shared__ float ysh[512];
    __shared__ float nsh[128];
    __shared__ float redA[2][128];
    __shared__ float redB[2][128];

    const int t = threadIdx.x;
    const int colbase = blockIdx.x * 128;
    const int rowgrp = blockIdx.y;            // 0..15
    const int rowbase = rowgrp * 512;

    const int wid = t >> 6;
    const int ch = wid & 1;                   // col half (64 cols)
    const int rh = wid >> 1;                  // row half (256 rows)
    const int lane = t & 63;
    const int lr = lane & 15;
    const int kb = lane >> 4;                 // k-block 0..3 = output row group

    // B fragments: 16 x bf16x8 (64 VGPR), from global (L2-hit), once; pinned.
    bf16x8 Bf[4][4];
#pragma unroll
    for (int j = 0; j < 4; ++j)
#pragma unroll
        for (int kk = 0; kk < 4; ++kk)
            Bf[j][kk] = *reinterpret_cast<const bf16x8*>(
                &xb[(size_t)(colbase + ch * 64 + j * 16 + lr) * DK + kk * 32 + kb * 8]);
#pragma unroll
    for (int j = 0; j < 4; ++j)
#pragma unroll
        for (int kk = 0; kk < 4; ++kk)
            asm volatile("" : "+v"(Bf[j][kk]));  // pin: not rematerializable

    if (PASS == 2) {
        if (t < 128) {
            float sp = 0.f;
#pragma unroll
            for (int r = 0; r < RG; ++r) sp += pp4in[r * BN + colbase + t];
            nsh[t] = LOG2E / fmaxf(sqrtf(sqrtf(sp)), 1e-12f);
        }
#pragma unroll
        for (int q = t; q < 512; q += 256) ysh[q] = y[rowbase + q];
        __syncthreads();
    }

    float inm[4];
    if (PASS == 2) {
#pragma unroll
        for (int j = 0; j < 4; ++j) inm[j] = nsh[ch * 64 + j * 16 + lr];
    }

    // A base for this wave/lane: rows rowbase + rh*256 + it*16 + lr
    const unsigned short* abase =
        catb + (size_t)(rowbase + rh * 256 + lr) * DK + kb * 8;

    bf16x8 a[4], an[4];
#pragma unroll
    for (int kk = 0; kk < 4; ++kk)
        a[kk] = *reinterpret_cast<const bf16x8*>(abase + kk * 32);

    float accA[4] = {0.f, 0.f, 0.f, 0.f};
    float accB[4] = {0.f, 0.f, 0.f, 0.f};

    for (int it = 0; it < NIT; ++it) {
        if (it < NIT - 1) {  // prefetch next 16-row strip (lands under MFMA)
            const unsigned short* nb = abase + (size_t)(it + 1) * 16 * DK;
#pragma unroll
            for (int kk = 0; kk < 4; ++kk)
                an[kk] = *reinterpret_cast<const bf16x8*>(nb + kk * 32);
        }

        f32x4 acc[4];
#pragma unroll
        for (int j = 0; j < 4; ++j) acc[j] = (f32x4){0.f, 0.f, 0.f, 0.f};

#pragma unroll
        for (int kk = 0; kk < 4; ++kk)
#pragma unroll
            for (int j = 0; j < 4; ++j)
                acc[j] = __builtin_amdgcn_mfma_f32_16x16x32_bf16(
                    a[kk], Bf[j][kk], acc[j], 0, 0, 0);

        if (PASS == 1) {
#pragma unroll
            for (int j = 0; j < 4; ++j)
#pragma unroll
                for (int r = 0; r < 4; ++r) {
                    const float v = acc[j][r];
                    const float v2 = v * v;
                    accA[j] = fmaf(v2, v2, accA[j]);
                }
        } else {
            const float4 yv = *reinterpret_cast<const float4*>(
                &ysh[rh * 256 + it * 16 + kb * 4]);
            const float yr4[4] = {yv.x, yv.y, yv.z, yv.w};
#pragma unroll
            for (int r = 0; r < 4; ++r) {
                const float yr = yr4[r];
#pragma unroll
                for (int j = 0; j < 4; ++j) {
                    const float e = exp2f(acc[j][r] * inm[j]);
                    accA[j] += e;
                    accB[j] = fmaf(yr, e, accB[j]);
                }
            }
        }

        if (it < NIT - 1) {
#pragma unroll
            for (int kk = 0; kk < 4; ++kk) a[kk] = an[kk];
        }
    }

    // reduce over output row groups (lane bits 4-5 = kb)
#pragma unroll
    for (int j = 0; j < 4; ++j) {
        accA[j] += __shfl_xor(accA[j], 16, 64);
        accA[j] += __shfl_xor(accA[j], 32, 64);
        if (PASS == 2) {
            accB[j] += __shfl_xor(accB[j], 16, 64);
            accB[j] += __shfl_xor(accB[j], 32, 64);
        }
    }
    if (lane < 16) {
#pragma unroll
        for (int j = 0; j < 4; ++j) {
            redA[rh][ch * 64 + j * 16 + lane] = accA[j];
            if (PASS == 2) redB[rh][ch * 64 + j * 16 + lane] = accB[j];
        }
    }
    __syncthreads();
    if (t < 128) {
        outA[(size_t)rowgrp * BN + colbase + t] = redA[0][t] + redA[1][t];
        if (PASS == 2)
            outB[(size_t)rowgrp * BN + colbase + t] = redB[0][t] + redB[1][t];
    }
}

// Final: 4 threads per output (one per source), xor-reduce
__global__ __launch_bounds__(256) void k_final(const float* __restrict__ x,
                                               const float* __restrict__ phi,
                                               const float* __restrict__ pZ,
                                               const float* __restrict__ pW,
                                               const float* __restrict__ bias,
                                               float* __restrict__ out) {
    const int g = blockIdx.x * 256 + threadIdx.x;
    const int b = g >> 2, s = g & 3;
    float dot = 0.f;
#pragma unroll
    for (int k = 0; k < DK; k += 4) {
        const float4 xv = ld4(&x[(size_t)b * DK + k]);
        const float4 pv = ld4(&phi[s * DK + k]);
        dot += xv.x * pv.x + xv.y * pv.y + xv.z * pv.z + xv.w * pv.w;
    }
    float W = 0.f, Z = 0.f;
#pragma unroll
    for (int r = 0; r < 4; ++r) {
        W += pW[(size_t)(4 * s + r) * BN + b];
        Z += pZ[(size_t)(4 * s + r) * BN + b];
    }
    float v = __expf(dot) * W;
    v += __shfl_xor(v, 1, 64);
    v += __shfl_xor(v, 2, 64);
    Z += __shfl_xor(Z, 1, 64);
    Z += __shfl_xor(Z, 2, 64);
    if (s == 0) out[b] = v / Z + bias[0];
}

extern "C" void kernel_launch(void* const* d_in, const int* in_sizes, int n_in,
                              void* d_out, int out_size, void* d_ws, size_t ws_size,
                              hipStream_t stream) {
    const float* x    = (const float*)d_in[0];
    const float* cat  = (const float*)d_in[1];
    const float* y    = (const float*)d_in[2];
    const float* phi  = (const float*)d_in[3];
    const float* bias = (const float*)d_in[4];
    float* out = (float*)d_out;

    char* ws = (char*)d_ws;
    unsigned short* xb   = (unsigned short*)ws;            // BN*DK bf16 (2MB)
    unsigned short* catb = xb + (size_t)BN * DK;           // 2MB
    float* pp4 = (float*)(catb + (size_t)NCAT * DK);       // RG*BN
    float* pZ  = pp4 + (size_t)RG * BN;                    // RG*BN
    float* pW  = pZ + (size_t)RG * BN;                     // RG*BN

    k_convert2<<<(BN * DK + NCAT * DK) / 8 / 256, 256, 0, stream>>>(x, cat, xb, catb);
    k_pass<1><<<dim3(BN / 128, RG), 256, 0, stream>>>(xb, catb, y, nullptr, pp4, nullptr);
    k_pass<2><<<dim3(BN / 128, RG), 256, 0, stream>>>(xb, catb, y, pp4, pZ, pW);
    k_final<<<BN * SRC / 256, 256, 0, stream>>>(x, phi, pZ, pW, bias, out);
}

// Round 10
// 75.876 us; speedup vs baseline: 1.2664x; 1.2664x over previous
//
#include <hip/hip_runtime.h>
#include <hip/hip_bf16.h>
#include <math.h>

typedef __bf16 bf16x8 __attribute__((ext_vector_type(8)));
typedef float f32x4 __attribute__((ext_vector_type(4)));

namespace {
constexpr int BN   = 8192;   // batch columns
constexpr int DK   = 128;    // feature dim
constexpr int NCAT = 8192;   // cat rows
constexpr int SRC  = 4;      // source chunks
constexpr int RG   = 8;      // row groups (1024 rows each)
constexpr int TROWS = 64;    // rows per LDS tile
constexpr int NT   = 16;     // tiles per rowgroup (1024/64)
constexpr float LOG2E = 1.4426950408889634f;
}

__device__ __forceinline__ float4 ld4(const float* p) {
    return *reinterpret_cast<const float4*>(p);
}

// async 16B global -> LDS (wave-uniform dest base + lane*16)
__device__ __forceinline__ void load_lds16(const unsigned short* g, unsigned short* l) {
    __builtin_amdgcn_global_load_lds(
        (const __attribute__((address_space(1))) void*)g,
        (__attribute__((address_space(3))) void*)l, 16, 0, 0);
}

// fp32 -> bf16 for x (row-major) and cat (64-row-tile-major, XOR-pre-swizzled so a
// LINEAR global_load_lds produces the swizzled LDS layout the MFMA reads expect).
__global__ __launch_bounds__(256) void k_convert2(const float* __restrict__ x,
                                                  const float* __restrict__ cat,
                                                  unsigned short* __restrict__ xb,
                                                  unsigned short* __restrict__ catb) {
    const int i = blockIdx.x * 256 + threadIdx.x;
    const int nx = BN * DK / 8;
    const float* src;
    unsigned short* dst;
    int j;
    size_t dchunk;
    if (i < nx) {
        src = x; dst = xb; j = i; dchunk = (size_t)j;
    } else {
        src = cat; dst = catb; j = i - nx;
        const int r = j >> 4, c = j & 15;      // row, 16B-chunk within row
        const int rt = r >> 6, r6 = r & 63;    // 64-row tile, row within tile
        dchunk = (size_t)rt * 1024 + r6 * 16 + (c ^ (r6 & 7));
    }
    const float4 a = ld4(src + (size_t)j * 8);
    const float4 b = ld4(src + (size_t)j * 8 + 4);
    float vals[8] = {a.x, a.y, a.z, a.w, b.x, b.y, b.z, b.w};
    union { unsigned short u[8]; uint4 v; } o;
#pragma unroll
    for (int q = 0; q < 8; ++q) {
        __hip_bfloat16 h = __float2bfloat16(vals[q]);
        o.u[q] = *reinterpret_cast<unsigned short*>(&h);
    }
    *reinterpret_cast<uint4*>(&dst[dchunk * 8]) = o.v;
}

// MFMA pass over 128 cols x 1024 rows. ROW-SPLIT: each of 4 waves owns a
// 16-row slice of each 64-row A-tile x ALL 128 cols. B fragments (Bf[8][4],
// 128 regs) loaded from global once and PINNED (empty asm) so the allocator
// keeps them resident (AGPR). A double-buffered in LDS via global_load_lds
// (pre-swizzled source): per tile = 4 ds_read_b128 + 32 MFMA per wave, one
// barrier. Zero A-read duplication, zero B LDS traffic -> MFMA-bound.
// No softmax max needed: |d|/norm4 <= 1 provably (norm4 >= max|d|).
// PASS==1: outA = partial sum(d^4)
// PASS==2: outA = partial Z, outB = partial sum(y*exp); norms from pp4in in-block
template <int PASS>
__global__ __launch_bounds__(256, 2) void k_pass(
    const unsigned short* __restrict__ xb,    // [BN][DK] bf16 row-major
    const unsigned short* __restrict__ catb,  // 64-row-tile-major pre-swizzled bf16
    const float* __restrict__ y,
    const float* __restrict__ pp4in,          // pass2: [RG][BN]
    float* __restrict__ outA,
    float* __restrict__ outB) {
    __shared__ __align__(16) unsigned short As[2][TROWS * DK];  // 2 x 16 KB
    __shared__ float nsh[128];
    __shared__ float redA[4][128];
    __shared__ float redB[4][128];

    const int t = threadIdx.x;
    const int colbase = blockIdx.x * 128;
    const int rowgrp = blockIdx.y;            // 0..7
    const int rowbase = rowgrp * 1024;
    const int tile0 = rowgrp * NT;            // global 64-row tile index base

    const int wid = t >> 6;                   // wave owns rows wid*16..+15 per tile
    const int lane = t & 63;
    const int lr = lane & 15;
    const int kb = lane >> 4;                 // k-block 0..3

    // issue tile-0 async loads immediately (land by the prologue barrier)
#pragma unroll
    for (int q = 0; q < 4; ++q)
        load_lds16(catb + ((size_t)tile0 * 1024 + (wid * 4 + q) * 64 + lane) * 8,
                   &As[0][(wid * 4 + q) * 64 * 8]);

    // B fragments: 32 x bf16x8 (128 regs) from global (L2-hit), once; pinned.
    bf16x8 Bf[8][4];
#pragma unroll
    for (int j = 0; j < 8; ++j)
#pragma unroll
        for (int kk = 0; kk < 4; ++kk)
            Bf[j][kk] = *reinterpret_cast<const bf16x8*>(
                &xb[(size_t)(colbase + j * 16 + lr) * DK + kk * 32 + kb * 8]);
#pragma unroll
    for (int j = 0; j < 8; ++j)
#pragma unroll
        for (int kk = 0; kk < 4; ++kk)
            asm volatile("" : "+v"(Bf[j][kk]));  // pin: not rematerializable

    if (PASS == 2 && t < 128) {
        float sp = 0.f;
#pragma unroll
        for (int r = 0; r < RG; ++r) sp += pp4in[r * BN + colbase + t];
        nsh[t] = LOG2E / fmaxf(sqrtf(sqrtf(sp)), 1e-12f);
    }
    __syncthreads();  // As[0] staged (vmcnt drain) + nsh ready

    float inm[8];
    if (PASS == 2) {
#pragma unroll
        for (int j = 0; j < 8; ++j) inm[j] = nsh[j * 16 + lr];
    }

    float accA[8] = {0.f, 0.f, 0.f, 0.f, 0.f, 0.f, 0.f, 0.f};
    float accB[8] = {0.f, 0.f, 0.f, 0.f, 0.f, 0.f, 0.f, 0.f};

    for (int tl = 0; tl < NT; ++tl) {
        const int cur = tl & 1, nxt = cur ^ 1;
        if (tl < NT - 1) {  // async-stage next tile; completes at tile-end barrier
#pragma unroll
            for (int q = 0; q < 4; ++q)
                load_lds16(catb + ((size_t)(tile0 + tl + 1) * 1024 +
                                   (wid * 4 + q) * 64 + lane) * 8,
                           &As[nxt][(wid * 4 + q) * 64 * 8]);
        }
        float4 yv;
        if (PASS == 2)  // issued early, consumed after MFMA cluster
            yv = ld4(&y[rowbase + tl * 64 + wid * 16 + kb * 4]);

        // this wave's 16-row A slice: 4 swizzled ds_read_b128
        bf16x8 a[4];
        const int row = wid * 16 + lr;
#pragma unroll
        for (int kk = 0; kk < 4; ++kk)
            a[kk] = *reinterpret_cast<const bf16x8*>(
                &As[cur][row * 128 + (((kk * 4 + kb) ^ (lr & 7)) * 8)]);

        f32x4 acc[8];
#pragma unroll
        for (int j = 0; j < 8; ++j) acc[j] = (f32x4){0.f, 0.f, 0.f, 0.f};
#pragma unroll
        for (int kk = 0; kk < 4; ++kk)
#pragma unroll
            for (int j = 0; j < 8; ++j)
                acc[j] = __builtin_amdgcn_mfma_f32_16x16x32_bf16(
                    a[kk], Bf[j][kk], acc[j], 0, 0, 0);

        if (PASS == 1) {
#pragma unroll
            for (int j = 0; j < 8; ++j)
#pragma unroll
                for (int r = 0; r < 4; ++r) {
                    const float v = acc[j][r];
                    const float v2 = v * v;
                    accA[j] = fmaf(v2, v2, accA[j]);
                }
        } else {
            const float yr4[4] = {yv.x, yv.y, yv.z, yv.w};
#pragma unroll
            for (int r = 0; r < 4; ++r) {
                const float yr = yr4[r];
#pragma unroll
                for (int j = 0; j < 8; ++j) {
                    const float e = exp2f(acc[j][r] * inm[j]);
                    accA[j] += e;
                    accB[j] = fmaf(yr, e, accB[j]);
                }
            }
        }
        __syncthreads();  // drains async loads; As[nxt] ready, As[cur] reusable
    }

    // reduce over k-block groups (lane bits 4-5) -> lanes 0-15 hold col partials
#pragma unroll
    for (int j = 0; j < 8; ++j) {
        accA[j] += __shfl_xor(accA[j], 16, 64);
        accA[j] += __shfl_xor(accA[j], 32, 64);
        if (PASS == 2) {
            accB[j] += __shfl_xor(accB[j], 16, 64);
            accB[j] += __shfl_xor(accB[j], 32, 64);
        }
    }
    if (lane < 16) {
#pragma unroll
        for (int j = 0; j < 8; ++j) {
            redA[wid][j * 16 + lane] = accA[j];
            if (PASS == 2) redB[wid][j * 16 + lane] = accB[j];
        }
    }
    __syncthreads();
    if (t < 128) {
        outA[(size_t)rowgrp * BN + colbase + t] =
            redA[0][t] + redA[1][t] + redA[2][t] + redA[3][t];
        if (PASS == 2)
            outB[(size_t)rowgrp * BN + colbase + t] =
                redB[0][t] + redB[1][t] + redB[2][t] + redB[3][t];
    }
}

// Final: 4 threads per output (one per source), xor-reduce
__global__ __launch_bounds__(256) void k_final(const float* __restrict__ x,
                                               const float* __restrict__ phi,
                                               const float* __restrict__ pZ,
                                               const float* __restrict__ pW,
                                               const float* __restrict__ bias,
                                               float* __restrict__ out) {
    const int g = blockIdx.x * 256 + threadIdx.x;
    const int b = g >> 2, s = g & 3;
    float dot = 0.f;
#pragma unroll
    for (int k = 0; k < DK; k += 4) {
        const float4 xv = ld4(&x[(size_t)b * DK + k]);
        const float4 pv = ld4(&phi[s * DK + k]);
        dot += xv.x * pv.x + xv.y * pv.y + xv.z * pv.z + xv.w * pv.w;
    }
    const float W = pW[(size_t)(2 * s) * BN + b] + pW[(size_t)(2 * s + 1) * BN + b];
    float v = __expf(dot) * W;
    float Z = pZ[(size_t)(2 * s) * BN + b] + pZ[(size_t)(2 * s + 1) * BN + b];
    v += __shfl_xor(v, 1, 64);
    v += __shfl_xor(v, 2, 64);
    Z += __shfl_xor(Z, 1, 64);
    Z += __shfl_xor(Z, 2, 64);
    if (s == 0) out[b] = v / Z + bias[0];
}

extern "C" void kernel_launch(void* const* d_in, const int* in_sizes, int n_in,
                              void* d_out, int out_size, void* d_ws, size_t ws_size,
                              hipStream_t stream) {
    const float* x    = (const float*)d_in[0];
    const float* cat  = (const float*)d_in[1];
    const float* y    = (const float*)d_in[2];
    const float* phi  = (const float*)d_in[3];
    const float* bias = (const float*)d_in[4];
    float* out = (float*)d_out;

    char* ws = (char*)d_ws;
    unsigned short* xb   = (unsigned short*)ws;            // BN*DK bf16 (2MB)
    unsigned short* catb = xb + (size_t)BN * DK;           // 2MB, pre-swizzled
    float* pp4 = (float*)(catb + (size_t)NCAT * DK);       // RG*BN
    float* pZ  = pp4 + (size_t)RG * BN;                    // RG*BN
    float* pW  = pZ + (size_t)RG * BN;                     // RG*BN

    k_convert2<<<(BN * DK + NCAT * DK) / 8 / 256, 256, 0, stream>>>(x, cat, xb, catb);
    k_pass<1><<<dim3(BN / 128, RG), 256, 0, stream>>>(xb, catb, y, nullptr, pp4, nullptr);
    k_pass<2><<<dim3(BN / 128, RG), 256, 0, stream>>>(xb, catb, y, pp4, pZ, pW);
    k_final<<<BN * SRC / 256, 256, 0, stream>>>(x, phi, pZ, pW, bias, out);
}

// Round 11
// 73.214 us; speedup vs baseline: 1.3125x; 1.0364x over previous
//
#include <hip/hip_runtime.h>
#include <hip/hip_bf16.h>
#include <math.h>

typedef __bf16 bf16x8 __attribute__((ext_vector_type(8)));
typedef float f32x4 __attribute__((ext_vector_type(4)));

namespace {
constexpr int BN   = 8192;   // batch columns
constexpr int DK   = 128;    // feature dim
constexpr int NCAT = 8192;   // cat rows
constexpr int SRC  = 4;      // source chunks
constexpr int RG   = 16;     // row groups (512 rows each)
constexpr int TROWS = 64;    // rows per LDS tile
constexpr int NT   = 8;      // tiles per rowgroup (512/64)
constexpr float LOG2E = 1.4426950408889634f;
}

__device__ __forceinline__ float4 ld4(const float* p) {
    return *reinterpret_cast<const float4*>(p);
}

// async 16B global -> LDS (wave-uniform dest base + lane*16)
__device__ __forceinline__ void load_lds16(const unsigned short* g, unsigned short* l) {
    __builtin_amdgcn_global_load_lds(
        (const __attribute__((address_space(1))) void*)g,
        (__attribute__((address_space(3))) void*)l, 16, 0, 0);
}

// fp32 -> bf16 for x (row-major) and cat (64-row-tile-major, XOR-pre-swizzled so a
// LINEAR global_load_lds produces the swizzled LDS layout the MFMA reads expect).
__global__ __launch_bounds__(256) void k_convert2(const float* __restrict__ x,
                                                  const float* __restrict__ cat,
                                                  unsigned short* __restrict__ xb,
                                                  unsigned short* __restrict__ catb) {
    const int i = blockIdx.x * 256 + threadIdx.x;
    const int nx = BN * DK / 8;
    const float* src;
    unsigned short* dst;
    int j;
    size_t dchunk;
    if (i < nx) {
        src = x; dst = xb; j = i; dchunk = (size_t)j;
    } else {
        src = cat; dst = catb; j = i - nx;
        const int r = j >> 4, c = j & 15;      // row, 16B-chunk within row
        const int rt = r >> 6, r6 = r & 63;    // 64-row tile, row within tile
        dchunk = (size_t)rt * 1024 + r6 * 16 + (c ^ (r6 & 7));
    }
    const float4 a = ld4(src + (size_t)j * 8);
    const float4 b = ld4(src + (size_t)j * 8 + 4);
    float vals[8] = {a.x, a.y, a.z, a.w, b.x, b.y, b.z, b.w};
    union { unsigned short u[8]; uint4 v; } o;
#pragma unroll
    for (int q = 0; q < 8; ++q) {
        __hip_bfloat16 h = __float2bfloat16(vals[q]);
        o.u[q] = *reinterpret_cast<unsigned short*>(&h);
    }
    *reinterpret_cast<uint4*>(&dst[dchunk * 8]) = o.v;
}

// MFMA pass over 128 cols x 512 rows. 2D wave split: wave (rh,ch) owns a
// 32-row x 64-col quadrant of each 64-row tile. Bf[4][4] (64 VGPR) pinned;
// acc[2][4]=32; total ~145 regs, fits 3 waves/SIMD (cap 170) -> 12 waves/CU.
// A double-buffered in LDS via global_load_lds (pre-swizzled source), one
// barrier per tile. LDS A-read amplification only 2x.
// No softmax max needed: |d|/norm4 <= 1 provably (norm4 >= max|d|).
// PASS==1: outA = partial sum(d^4)
// PASS==2: outA = partial Z, outB = partial sum(y*exp); norms from pp4in in-block
template <int PASS>
__global__ __launch_bounds__(256, 3) void k_pass(
    const unsigned short* __restrict__ xb,    // [BN][DK] bf16 row-major
    const unsigned short* __restrict__ catb,  // 64-row-tile-major pre-swizzled bf16
    const float* __restrict__ y,
    const float* __restrict__ pp4in,          // pass2: [RG][BN]
    float* __restrict__ outA,
    float* __restrict__ outB) {
    __shared__ __align__(16) unsigned short As[2][TROWS * DK];  // 2 x 16 KB
    __shared__ float nsh[128];
    __shared__ float redA[2][128];
    __shared__ float redB[2][128];

    const int t = threadIdx.x;
    const int colbase = blockIdx.x * 128;
    const int rowgrp = blockIdx.y;            // 0..15
    const int rowbase = rowgrp * 512;
    const int tile0 = rowgrp * NT;            // global 64-row tile index base

    const int wid = t >> 6;
    const int rh = wid >> 1;                  // row half: rows rh*32..+31 of tile
    const int ch = wid & 1;                   // col half: cols ch*64..+63
    const int lane = t & 63;
    const int lr = lane & 15;
    const int kb = lane >> 4;                 // k-block 0..3

    // issue tile-0 async loads immediately (land by the prologue barrier)
#pragma unroll
    for (int q = 0; q < 4; ++q)
        load_lds16(catb + ((size_t)tile0 * 1024 + (wid * 4 + q) * 64 + lane) * 8,
                   &As[0][(wid * 4 + q) * 64 * 8]);

    // B fragments: 16 x bf16x8 (64 VGPR) from global (L2-hit), once; pinned.
    bf16x8 Bf[4][4];
#pragma unroll
    for (int j = 0; j < 4; ++j)
#pragma unroll
        for (int kk = 0; kk < 4; ++kk)
            Bf[j][kk] = *reinterpret_cast<const bf16x8*>(
                &xb[(size_t)(colbase + ch * 64 + j * 16 + lr) * DK + kk * 32 + kb * 8]);
#pragma unroll
    for (int j = 0; j < 4; ++j)
#pragma unroll
        for (int kk = 0; kk < 4; ++kk)
            asm volatile("" : "+v"(Bf[j][kk]));  // pin: not rematerializable

    if (PASS == 2 && t < 128) {
        float sp = 0.f;
#pragma unroll
        for (int r = 0; r < RG; ++r) sp += pp4in[r * BN + colbase + t];
        nsh[t] = LOG2E / fmaxf(sqrtf(sqrtf(sp)), 1e-12f);
    }
    __syncthreads();  // As[0] staged (vmcnt drain) + nsh ready

    float inm[4];
    if (PASS == 2) {
#pragma unroll
        for (int j = 0; j < 4; ++j) inm[j] = nsh[ch * 64 + j * 16 + lr];
    }

    float accA[4] = {0.f, 0.f, 0.f, 0.f};
    float accB[4] = {0.f, 0.f, 0.f, 0.f};

    for (int tl = 0; tl < NT; ++tl) {
        const int cur = tl & 1, nxt = cur ^ 1;
        if (tl < NT - 1) {  // async-stage next tile; completes at tile-end barrier
#pragma unroll
            for (int q = 0; q < 4; ++q)
                load_lds16(catb + ((size_t)(tile0 + tl + 1) * 1024 +
                                   (wid * 4 + q) * 64 + lane) * 8,
                           &As[nxt][(wid * 4 + q) * 64 * 8]);
        }
        float4 yv0, yv1;
        if (PASS == 2) {  // issued early, consumed after MFMA cluster (L2 broadcast)
            yv0 = ld4(&y[rowbase + tl * 64 + rh * 32 + kb * 4]);
            yv1 = ld4(&y[rowbase + tl * 64 + rh * 32 + 16 + kb * 4]);
        }

        // this wave's 32-row A slice: 8 swizzled ds_read_b128
        bf16x8 a[2][4];
#pragma unroll
        for (int i = 0; i < 2; ++i) {
            const int row = rh * 32 + i * 16 + lr;
#pragma unroll
            for (int kk = 0; kk < 4; ++kk)
                a[i][kk] = *reinterpret_cast<const bf16x8*>(
                    &As[cur][row * 128 + (((kk * 4 + kb) ^ (lr & 7)) * 8)]);
        }

        f32x4 acc[2][4];
#pragma unroll
        for (int i = 0; i < 2; ++i)
#pragma unroll
            for (int j = 0; j < 4; ++j) acc[i][j] = (f32x4){0.f, 0.f, 0.f, 0.f};
#pragma unroll
        for (int kk = 0; kk < 4; ++kk)
#pragma unroll
            for (int i = 0; i < 2; ++i)
#pragma unroll
                for (int j = 0; j < 4; ++j)
                    acc[i][j] = __builtin_amdgcn_mfma_f32_16x16x32_bf16(
                        a[i][kk], Bf[j][kk], acc[i][j], 0, 0, 0);

        if (PASS == 1) {
#pragma unroll
            for (int i = 0; i < 2; ++i)
#pragma unroll
                for (int j = 0; j < 4; ++j)
#pragma unroll
                    for (int r = 0; r < 4; ++r) {
                        const float v = acc[i][j][r];
                        const float v2 = v * v;
                        accA[j] = fmaf(v2, v2, accA[j]);
                    }
        } else {
#pragma unroll
            for (int i = 0; i < 2; ++i) {
                const float4 yv = (i == 0) ? yv0 : yv1;
                const float yr4[4] = {yv.x, yv.y, yv.z, yv.w};
#pragma unroll
                for (int r = 0; r < 4; ++r) {
                    const float yr = yr4[r];
#pragma unroll
                    for (int j = 0; j < 4; ++j) {
                        const float e = exp2f(acc[i][j][r] * inm[j]);
                        accA[j] += e;
                        accB[j] = fmaf(yr, e, accB[j]);
                    }
                }
            }
        }
        __syncthreads();  // drains async loads; As[nxt] ready, As[cur] reusable
    }

    // reduce over k-block groups (lane bits 4-5) -> lanes 0-15 hold col partials
#pragma unroll
    for (int j = 0; j < 4; ++j) {
        accA[j] += __shfl_xor(accA[j], 16, 64);
        accA[j] += __shfl_xor(accA[j], 32, 64);
        if (PASS == 2) {
            accB[j] += __shfl_xor(accB[j], 16, 64);
            accB[j] += __shfl_xor(accB[j], 32, 64);
        }
    }
    if (lane < 16) {
#pragma unroll
        for (int j = 0; j < 4; ++j) {
            redA[rh][ch * 64 + j * 16 + lane] = accA[j];
            if (PASS == 2) redB[rh][ch * 64 + j * 16 + lane] = accB[j];
        }
    }
    __syncthreads();
    if (t < 128) {
        outA[(size_t)rowgrp * BN + colbase + t] = redA[0][t] + redA[1][t];
        if (PASS == 2)
            outB[(size_t)rowgrp * BN + colbase + t] = redB[0][t] + redB[1][t];
    }
}

// Final: 4 threads per output (one per source), xor-reduce
__global__ __launch_bounds__(256) void k_final(const float* __restrict__ x,
                                               const float* __restrict__ phi,
                                               const float* __restrict__ pZ,
                                               const float* __restrict__ pW,
                                               const float* __restrict__ bias,
                                               float* __restrict__ out) {
    const int g = blockIdx.x * 256 + threadIdx.x;
    const int b = g >> 2, s = g & 3;
    float dot = 0.f;
#pragma unroll
    for (int k = 0; k < DK; k += 4) {
        const float4 xv = ld4(&x[(size_t)b * DK + k]);
        const float4 pv = ld4(&phi[s * DK + k]);
        dot += xv.x * pv.x + xv.y * pv.y + xv.z * pv.z + xv.w * pv.w;
    }
    float W = 0.f, Z = 0.f;
#pragma unroll
    for (int r = 0; r < 4; ++r) {
        W += pW[(size_t)(4 * s + r) * BN + b];
        Z += pZ[(size_t)(4 * s + r) * BN + b];
    }
    float v = __expf(dot) * W;
    v += __shfl_xor(v, 1, 64);
    v += __shfl_xor(v, 2, 64);
    Z += __shfl_xor(Z, 1, 64);
    Z += __shfl_xor(Z, 2, 64);
    if (s == 0) out[b] = v / Z + bias[0];
}

extern "C" void kernel_launch(void* const* d_in, const int* in_sizes, int n_in,
                              void* d_out, int out_size, void* d_ws, size_t ws_size,
                              hipStream_t stream) {
    const float* x    = (const float*)d_in[0];
    const float* cat  = (const float*)d_in[1];
    const float* y    = (const float*)d_in[2];
    const float* phi  = (const float*)d_in[3];
    const float* bias = (const float*)d_in[4];
    float* out = (float*)d_out;

    char* ws = (char*)d_ws;
    unsigned short* xb   = (unsigned short*)ws;            // BN*DK bf16 (2MB)
    unsigned short* catb = xb + (size_t)BN * DK;           // 2MB, pre-swizzled
    float* pp4 = (float*)(catb + (size_t)NCAT * DK);       // RG*BN
    float* pZ  = pp4 + (size_t)RG * BN;                    // RG*BN
    float* pW  = pZ + (size_t)RG * BN;                     // RG*BN

    k_convert2<<<(BN * DK + NCAT * DK) / 8 / 256, 256, 0, stream>>>(x, cat, xb, catb);
    k_pass<1><<<dim3(BN / 128, RG), 256, 0, stream>>>(xb, catb, y, nullptr, pp4, nullptr);
    k_pass<2><<<dim3(BN / 128, RG), 256, 0, stream>>>(xb, catb, y, pp4, pZ, pW);
    k_final<<<BN * SRC / 256, 256, 0, stream>>>(x, phi, pZ, pW, bias, out);
}

// Round 12
// 68.954 us; speedup vs baseline: 1.3935x; 1.0618x over previous
//
#include <hip/hip_runtime.h>
#include <hip/hip_bf16.h>
#include <math.h>

typedef __bf16 bf16x8 __attribute__((ext_vector_type(8)));
typedef float f32x4 __attribute__((ext_vector_type(4)));

namespace {
constexpr int BN   = 8192;   // batch columns
constexpr int DK   = 128;    // feature dim
constexpr int NCAT = 8192;   // cat rows
constexpr int SRC  = 4;      // source chunks
constexpr int RG   = 16;     // row groups (512 rows each)
constexpr int TROWS = 64;    // rows per LDS tile
constexpr int NT   = 8;      // tiles per rowgroup (512/64)
constexpr float LOG2E = 1.4426950408889634f;
}

__device__ __forceinline__ float4 ld4(const float* p) {
    return *reinterpret_cast<const float4*>(p);
}

// async 16B global -> LDS (wave-uniform dest base + lane*16)
__device__ __forceinline__ void load_lds16(const unsigned short* g, unsigned short* l) {
    __builtin_amdgcn_global_load_lds(
        (const __attribute__((address_space(1))) void*)g,
        (__attribute__((address_space(3))) void*)l, 16, 0, 0);
}

// stage one 64-row tile (this wave's quarter: 4 x 1KB chunks)
__device__ __forceinline__ void stage_tile(const unsigned short* __restrict__ src,
                                           unsigned short* dst, int wid, int lane) {
#pragma unroll
    for (int q = 0; q < 4; ++q)
        load_lds16(src + ((size_t)((wid * 4 + q) * 64 + lane)) * 8,
                   dst + (size_t)(wid * 4 + q) * 512);
}

// fp32 -> bf16 for x (row-major) and cat (64-row-tile-major, XOR-pre-swizzled so a
// LINEAR global_load_lds produces the swizzled LDS layout the MFMA reads expect).
__global__ __launch_bounds__(256) void k_convert2(const float* __restrict__ x,
                                                  const float* __restrict__ cat,
                                                  unsigned short* __restrict__ xb,
                                                  unsigned short* __restrict__ catb) {
    const int i = blockIdx.x * 256 + threadIdx.x;
    const int nx = BN * DK / 8;
    const float* src;
    unsigned short* dst;
    int j;
    size_t dchunk;
    if (i < nx) {
        src = x; dst = xb; j = i; dchunk = (size_t)j;
    } else {
        src = cat; dst = catb; j = i - nx;
        const int r = j >> 4, c = j & 15;      // row, 16B-chunk within row
        const int rt = r >> 6, r6 = r & 63;    // 64-row tile, row within tile
        dchunk = (size_t)rt * 1024 + r6 * 16 + (c ^ (r6 & 7));
    }
    const float4 a = ld4(src + (size_t)j * 8);
    const float4 b = ld4(src + (size_t)j * 8 + 4);
    float vals[8] = {a.x, a.y, a.z, a.w, b.x, b.y, b.z, b.w};
    union { unsigned short u[8]; uint4 v; } o;
#pragma unroll
    for (int q = 0; q < 8; ++q) {
        __hip_bfloat16 h = __float2bfloat16(vals[q]);
        o.u[q] = *reinterpret_cast<unsigned short*>(&h);
    }
    *reinterpret_cast<uint4*>(&dst[dchunk * 8]) = o.v;
}

// MFMA pass over 128 cols x 512 rows. Wave (rh,ch) owns a 32-row x 64-col
// quadrant; Bf[4][4] pinned in regs. A triple-buffered in LDS via
// global_load_lds with COUNTED vmcnt pipeline (T3/T4): prefetch depth 2,
// raw s_barrier, s_waitcnt vmcnt(4) in steady state (never 0 mid-loop).
// Fully unrolled NT=8 -> buffer indices & waits are compile-time.
// No softmax max needed: |d|/norm4 <= 1 provably (norm4 >= max|d|).
// PASS==1: outA = partial sum(d^4)
// PASS==2: outA = partial Z, outB = partial sum(y*exp); norms from pp4in in-block
template <int PASS>
__global__ __launch_bounds__(256, 3) void k_pass(
    const unsigned short* __restrict__ xb,    // [BN][DK] bf16 row-major
    const unsigned short* __restrict__ catb,  // 64-row-tile-major pre-swizzled bf16
    const float* __restrict__ y,
    const float* __restrict__ pp4in,          // pass2: [RG][BN]
    float* __restrict__ outA,
    float* __restrict__ outB) {
    __shared__ __align__(16) unsigned short As[3][TROWS * DK];  // 3 x 16 KB
    __shared__ float ysh[512];
    __shared__ float nsh[128];
    __shared__ float redA[2][128];
    __shared__ float redB[2][128];

    const int t = threadIdx.x;
    const int colbase = blockIdx.x * 128;
    const int rowgrp = blockIdx.y;            // 0..15
    const int tile0 = rowgrp * NT;

    const int wid = t >> 6;
    const int rh = wid >> 1;                  // row half: rows rh*32..+31 of tile
    const int ch = wid & 1;                   // col half: cols ch*64..+63
    const int lane = t & 63;
    const int lr = lane & 15;
    const int kb = lane >> 4;                 // k-block 0..3

    // B fragments: 16 x bf16x8 (64 VGPR) from global (L2-hit), once; pinned.
    bf16x8 Bf[4][4];
#pragma unroll
    for (int j = 0; j < 4; ++j)
#pragma unroll
        for (int kk = 0; kk < 4; ++kk)
            Bf[j][kk] = *reinterpret_cast<const bf16x8*>(
                &xb[(size_t)(colbase + ch * 64 + j * 16 + lr) * DK + kk * 32 + kb * 8]);
#pragma unroll
    for (int j = 0; j < 4; ++j)
#pragma unroll
        for (int kk = 0; kk < 4; ++kk)
            asm volatile("" : "+v"(Bf[j][kk]));  // pin: forces materialization + wait

    if (PASS == 2) {
        if (t < 128) {
            float sp = 0.f;
#pragma unroll
            for (int r = 0; r < RG; ++r) sp += pp4in[r * BN + colbase + t];
            nsh[t] = LOG2E / fmaxf(sqrtf(sqrtf(sp)), 1e-12f);
        }
#pragma unroll
        for (int q = t; q < 512; q += 256) ysh[q] = y[rowgrp * 512 + q];
    }

    // issue tiles 0 and 1 AFTER the pin (so the pin's implicit vmem wait
    // doesn't drain them); exactly 8 vmem ops in flight per wave now.
    stage_tile(catb + (size_t)tile0 * 8192, &As[0][0], wid, lane);
    stage_tile(catb + (size_t)(tile0 + 1) * 8192, &As[1][0], wid, lane);

    // make nsh/ysh ds_writes visible to all waves (does NOT drain vmcnt)
    asm volatile("s_waitcnt lgkmcnt(0)" ::: "memory");
    __builtin_amdgcn_s_barrier();

    float inm[4];
    if (PASS == 2) {
#pragma unroll
        for (int j = 0; j < 4; ++j) inm[j] = nsh[ch * 64 + j * 16 + lr];
    }

    float accA[4] = {0.f, 0.f, 0.f, 0.f};
    float accB[4] = {0.f, 0.f, 0.f, 0.f};

#pragma unroll
    for (int tl = 0; tl < NT; ++tl) {
        // wait for OWN tile-tl loads (tile tl+1's 4 stay in flight), then sync:
        // after the barrier every wave's tile-tl loads are complete.
        if (tl < NT - 1)
            asm volatile("s_waitcnt vmcnt(4)" ::: "memory");
        else
            asm volatile("s_waitcnt vmcnt(0)" ::: "memory");
        __builtin_amdgcn_s_barrier();
        // issue tile tl+2 into As[(tl+2)%3] (= As[(tl-1)%3], consumed at tl-1;
        // everyone is past that compute since they reached this barrier)
        if (tl < NT - 2)
            stage_tile(catb + (size_t)(tile0 + tl + 2) * 8192,
                       &As[(tl + 2) % 3][0], wid, lane);

        // this wave's 32-row A slice: 8 swizzled ds_read_b128 (compile-time buffer)
        bf16x8 a[2][4];
#pragma unroll
        for (int i = 0; i < 2; ++i) {
            const int row = rh * 32 + i * 16 + lr;
#pragma unroll
            for (int kk = 0; kk < 4; ++kk)
                a[i][kk] = *reinterpret_cast<const bf16x8*>(
                    &As[tl % 3][row * 128 + (((kk * 4 + kb) ^ (lr & 7)) * 8)]);
        }

        f32x4 acc[2][4];
#pragma unroll
        for (int i = 0; i < 2; ++i)
#pragma unroll
            for (int j = 0; j < 4; ++j) acc[i][j] = (f32x4){0.f, 0.f, 0.f, 0.f};

        __builtin_amdgcn_s_setprio(1);
#pragma unroll
        for (int kk = 0; kk < 4; ++kk)
#pragma unroll
            for (int i = 0; i < 2; ++i)
#pragma unroll
                for (int j = 0; j < 4; ++j)
                    acc[i][j] = __builtin_amdgcn_mfma_f32_16x16x32_bf16(
                        a[i][kk], Bf[j][kk], acc[i][j], 0, 0, 0);
        __builtin_amdgcn_s_setprio(0);

        if (PASS == 1) {
#pragma unroll
            for (int i = 0; i < 2; ++i)
#pragma unroll
                for (int j = 0; j < 4; ++j)
#pragma unroll
                    for (int r = 0; r < 4; ++r) {
                        const float v = acc[i][j][r];
                        const float v2 = v * v;
                        accA[j] = fmaf(v2, v2, accA[j]);
                    }
        } else {
#pragma unroll
            for (int i = 0; i < 2; ++i) {
                const float4 yv = *reinterpret_cast<const float4*>(
                    &ysh[tl * 64 + rh * 32 + i * 16 + kb * 4]);
                const float yr4[4] = {yv.x, yv.y, yv.z, yv.w};
#pragma unroll
                for (int r = 0; r < 4; ++r) {
                    const float yr = yr4[r];
#pragma unroll
                    for (int j = 0; j < 4; ++j) {
                        const float e = exp2f(acc[i][j][r] * inm[j]);
                        accA[j] += e;
                        accB[j] = fmaf(yr, e, accB[j]);
                    }
                }
            }
        }
    }

    // reduce over k-block groups (lane bits 4-5) -> lanes 0-15 hold col partials
#pragma unroll
    for (int j = 0; j < 4; ++j) {
        accA[j] += __shfl_xor(accA[j], 16, 64);
        accA[j] += __shfl_xor(accA[j], 32, 64);
        if (PASS == 2) {
            accB[j] += __shfl_xor(accB[j], 16, 64);
            accB[j] += __shfl_xor(accB[j], 32, 64);
        }
    }
    if (lane < 16) {
#pragma unroll
        for (int j = 0; j < 4; ++j) {
            redA[rh][ch * 64 + j * 16 + lane] = accA[j];
            if (PASS == 2) redB[rh][ch * 64 + j * 16 + lane] = accB[j];
        }
    }
    __syncthreads();
    if (t < 128) {
        outA[(size_t)rowgrp * BN + colbase + t] = redA[0][t] + redA[1][t];
        if (PASS == 2)
            outB[(size_t)rowgrp * BN + colbase + t] = redB[0][t] + redB[1][t];
    }
}

// Final: 4 threads per output (one per source), xor-reduce
__global__ __launch_bounds__(256) void k_final(const float* __restrict__ x,
                                               const float* __restrict__ phi,
                                               const float* __restrict__ pZ,
                                               const float* __restrict__ pW,
                                               const float* __restrict__ bias,
                                               float* __restrict__ out) {
    const int g = blockIdx.x * 256 + threadIdx.x;
    const int b = g >> 2, s = g & 3;
    float dot = 0.f;
#pragma unroll
    for (int k = 0; k < DK; k += 4) {
        const float4 xv = ld4(&x[(size_t)b * DK + k]);
        const float4 pv = ld4(&phi[s * DK + k]);
        dot += xv.x * pv.x + xv.y * pv.y + xv.z * pv.z + xv.w * pv.w;
    }
    float W = 0.f, Z = 0.f;
#pragma unroll
    for (int r = 0; r < 4; ++r) {
        W += pW[(size_t)(4 * s + r) * BN + b];
        Z += pZ[(size_t)(4 * s + r) * BN + b];
    }
    float v = __expf(dot) * W;
    v += __shfl_xor(v, 1, 64);
    v += __shfl_xor(v, 2, 64);
    Z += __shfl_xor(Z, 1, 64);
    Z += __shfl_xor(Z, 2, 64);
    if (s == 0) out[b] = v / Z + bias[0];
}

extern "C" void kernel_launch(void* const* d_in, const int* in_sizes, int n_in,
                              void* d_out, int out_size, void* d_ws, size_t ws_size,
                              hipStream_t stream) {
    const float* x    = (const float*)d_in[0];
    const float* cat  = (const float*)d_in[1];
    const float* y    = (const float*)d_in[2];
    const float* phi  = (const float*)d_in[3];
    const float* bias = (const float*)d_in[4];
    float* out = (float*)d_out;

    char* ws = (char*)d_ws;
    unsigned short* xb   = (unsigned short*)ws;            // BN*DK bf16 (2MB)
    unsigned short* catb = xb + (size_t)BN * DK;           // 2MB, pre-swizzled
    float* pp4 = (float*)(catb + (size_t)NCAT * DK);       // RG*BN
    float* pZ  = pp4 + (size_t)RG * BN;                    // RG*BN
    float* pW  = pZ + (size_t)RG * BN;                     // RG*BN

    k_convert2<<<(BN * DK + NCAT * DK) / 8 / 256, 256, 0, stream>>>(x, cat, xb, catb);
    k_pass<1><<<dim3(BN / 128, RG), 256, 0, stream>>>(xb, catb, y, nullptr, pp4, nullptr);
    k_pass<2><<<dim3(BN / 128, RG), 256, 0, stream>>>(xb, catb, y, pp4, pZ, pW);
    k_final<<<BN * SRC / 256, 256, 0, stream>>>(x, phi, pZ, pW, bias, out);
}